// Round 4
// baseline (3142.076 us; speedup 1.0000x reference)
//
#include <hip/hip_runtime.h>
#include <hip/hip_cooperative_groups.h>
#include <math.h>

namespace cg = cooperative_groups;

#define NN 4096
#define DD 512
#define NSL 16
#define NBATCH 16
#define SCALE_F 0.044194173824159216f
#define LN_EPS_F 1e-5f
#define ATTN_EPS_F 1e-8f
#define NBLK 512

typedef float4 f4;

__device__ __forceinline__ float dot4f(f4 a, f4 b){
    return a.x*b.x + a.y*b.y + a.z*b.z + a.w*b.w;
}

struct Params {
    const float *kin, *vin, *mu, *prompts;
    const float *Wq, *bq, *Wih, *bih, *Whh, *bhh, *W1, *b1, *W2, *b2;
    const float *gk, *bk, *gv, *bv, *gs, *bs, *gff, *bff;
    float *slots, *slots2, *sbuf, *qg, *upd, *hid, *gp, *w;
    float *vmu, *vrstd, *kmu, *krstd, *C1p, *C2p, *Sp, *Mp, *Uwp;
    float *out_slots, *out_attn, *pf, *sf, *sf2;
};

__device__ void run_phase(const Params& p, int phase, int it){
    __shared__ __align__(16) float smem[2560];
    const int bx = blockIdx.x, t = threadIdx.x;
    const int lane = t & 63, wv = t >> 6;

    switch (phase){

    case 0: { // slots bcast + per-row stats of v AND k (coalesced, 16 lanes/row)
        int idx = bx*256 + t;
        if (idx < 32768)
            ((f4*)p.slots)[idx] = ((const f4*)p.mu)[idx & 2047];
        int sub = t & 15;          // lane-within-row
        int rloc = t >> 4;         // 16 rows per pass
        for (int half = 0; half < 2; half++){
            const float* src = half ? p.kin : p.vin;
            float* dmu  = half ? p.kmu : p.vmu;
            float* drs  = half ? p.krstd : p.vrstd;
            for (int pass = 0; pass < 8; pass++){
                int row = bx*128 + pass*16 + rloc;
                const f4* r4 = (const f4*)(src + (size_t)row*DD);
                float s = 0.f, ss = 0.f;
#pragma unroll
                for (int k2 = 0; k2 < 8; k2++){
                    f4 x = r4[sub + k2*16];
                    s  += x.x+x.y+x.z+x.w;
                    ss += x.x*x.x+x.y*x.y+x.z*x.z+x.w*x.w;
                }
                for (int o = 1; o < 16; o <<= 1){
                    s += __shfl_xor(s, o); ss += __shfl_xor(ss, o);
                }
                if (sub == 0){
                    float m = s*(1.f/DD);
                    dmu[row] = m;
                    drs[row] = rsqrtf(ss*(1.f/DD) - m*m + LN_EPS_F);
                }
            }
        }
    } break;

    case 1: { // LN(slots; gs,bs) -> sbuf  (row = bx < 256)
        if (bx >= 256) break;
        f4 v = {0.f,0.f,0.f,0.f};
        float s = 0.f, ss = 0.f;
        if (t < 128){
            v = ((const f4*)(p.slots + (size_t)bx*DD))[t];
            s = v.x+v.y+v.z+v.w;
            ss = v.x*v.x+v.y*v.y+v.z*v.z+v.w*v.w;
        }
        for (int o = 32; o; o >>= 1){ s += __shfl_down(s,o); ss += __shfl_down(ss,o); }
        if (lane == 0){ smem[wv] = s; smem[4+wv] = ss; }
        __syncthreads();
        float S = smem[0]+smem[1], SS = smem[4]+smem[5];
        float mu = S*(1.f/DD);
        float rstd = rsqrtf(SS*(1.f/DD) - mu*mu + LN_EPS_F);
        if (t < 128){
            f4 gg = ((const f4*)p.gs)[t], cc4 = ((const f4*)p.bs)[t], o4;
            o4.x = (v.x-mu)*rstd*gg.x + cc4.x;
            o4.y = (v.y-mu)*rstd*gg.y + cc4.y;
            o4.z = (v.z-mu)*rstd*gg.z + cc4.z;
            o4.w = (v.w-mu)*rstd*gg.w + cc4.w;
            ((f4*)(p.sbuf + (size_t)bx*DD))[t] = o4;
        }
    } break;

    case 2: { // q = sbuf@Wq^T + bq ; qg = q*gk ; C1/C2 partials. 1 row/wave.
        int cc = bx & 7, mg = bx >> 3;            // 8 x 64
        int c = cc*64 + lane;
        int m = mg*4 + wv;                        // 0..255
        const f4* w4 = (const f4*)(p.Wq + (size_t)c*DD);
        const f4* s4 = (const f4*)(p.sbuf + (size_t)m*DD);
        float a0 = 0.f;
        for (int k = 0; k < 128; k++) a0 += dot4f(s4[k], w4[k]);
        float q0 = a0 + p.bq[c];
        float qg0 = q0 * p.gk[c];
        p.qg[(size_t)m*DD + c] = qg0;
        float r1 = qg0, r2 = q0 * p.bk[c];
        for (int o = 32; o; o >>= 1){ r1 += __shfl_down(r1,o); r2 += __shfl_down(r2,o); }
        if (lane == 0){ p.C1p[cc*256 + m] = r1; p.C2p[cc*256 + m] = r2; }
    } break;

    case 3: { // QK^T + inverted softmax. wave = (b, 32 j's); lane = (K-slice, slot i)
        int gw = bx*4 + wv;                        // 0..2047
        int b  = gw >> 7;
        int j0 = (gw & 127) * 32;
        int rep = lane >> 4, i = lane & 15;
        const f4* qrow = (const f4*)(p.qg + ((size_t)(b*NSL + i))*DD + rep*128);
        f4 qf[32];
#pragma unroll
        for (int m2 = 0; m2 < 32; m2++) qf[m2] = qrow[m2];
        float c1 = 0.f, c2 = 0.f;
#pragma unroll
        for (int k2 = 0; k2 < 8; k2++){
            c1 += p.C1p[k2*256 + b*NSL + i];
            c2 += p.C2p[k2*256 + b*NSL + i];
        }
        float Sacc = 0.f, Macc = 0.f;
        for (int jj = 0; jj < 32; jj++){
            int j = j0 + jj;
            const f4* kr = (const f4*)(p.kin + ((size_t)b*NN + j)*DD) + rep*32;
            float acc = 0.f;
#pragma unroll
            for (int dd = 0; dd < 32; dd++)
                acc += dot4f(qf[dd], kr[dd]);
            acc += __shfl_xor(acc, 16);
            acc += __shfl_xor(acc, 32);
            float kmuv = p.kmu[(size_t)b*NN + j];
            float krsv = p.krstd[(size_t)b*NN + j];
            float dv = SCALE_F*(krsv*(acc - kmuv*c1) + c2);
            float mx = dv;
            for (int o = 1; o < 16; o <<= 1) mx = fmaxf(mx, __shfl_xor(mx, o));
            float e = __expf(dv - mx), se = e;
            for (int o = 1; o < 16; o <<= 1) se += __shfl_xor(se, o);
            float a = e/se + ATTN_EPS_F;
            float rv = p.vrstd[(size_t)b*NN + j];
            float wval = a * rv;
            Sacc += a;
            Macc += wval * p.vmu[(size_t)b*NN + j];
            if (lane < 32){
                float val = (lane < 16) ? a : wval;
                float* bp = (lane < 16) ? p.out_attn : p.w;
                bp[((size_t)b*NSL + i)*NN + j] = val;
            }
        }
        if (lane < 16)
            p.Sp[((size_t)b*NSL + i)*128 + (gw & 127)] = Sacc;
        else if (lane < 32)
            p.Mp[((size_t)b*NSL + i)*128 + (gw & 127)] = Macc;
    } break;

    case 4: { // Uw partials = w-tile @ v-tile. block = (b, jc of 32), 128 j each
        int b = bx & 15, jc = bx >> 4;
        int jbase = jc*128;
        for (int idx = t; idx < 2048; idx += 256){
            int i = idx >> 7, jj = idx & 127;
            smem[jj*20 + i] = p.w[((size_t)b*NSL + i)*NN + jbase + jj];
        }
        __syncthreads();
        f4 ax[4], ay[4];
#pragma unroll
        for (int g2 = 0; g2 < 4; g2++){ ax[g2] = f4{0,0,0,0}; ay[g2] = f4{0,0,0,0}; }
        const float2* v2 = (const float2*)(p.vin + ((size_t)b*NN + jbase)*DD);
#pragma unroll 2
        for (int jj = 0; jj < 128; jj++){
            float2 vv = v2[(size_t)jj*256 + t];
            const f4* wl4 = (const f4*)smem + jj*5;
#pragma unroll
            for (int g2 = 0; g2 < 4; g2++){
                f4 wq = wl4[g2];
                ax[g2].x += wq.x*vv.x; ax[g2].y += wq.y*vv.x; ax[g2].z += wq.z*vv.x; ax[g2].w += wq.w*vv.x;
                ay[g2].x += wq.x*vv.y; ay[g2].y += wq.y*vv.y; ay[g2].z += wq.z*vv.y; ay[g2].w += wq.w*vv.y;
            }
        }
#pragma unroll
        for (int g2 = 0; g2 < 4; g2++){
            const float* px = (const float*)&ax[g2];
            const float* py = (const float*)&ay[g2];
#pragma unroll
            for (int c4 = 0; c4 < 4; c4++){
                int i = g2*4 + c4;
                float2 o2; o2.x = px[c4]; o2.y = py[c4];
                *(float2*)(p.Uwp + ((size_t)(b*NSL + i)*32 + jc)*DD + 2*t) = o2;
            }
        }
    } break;

    case 5: { // S,M reduce + updates  (row m = bx < 256)
        int m = bx; if (m >= 256) break;
        float s = 0.f, mmv = 0.f;
        if (t < 128){ s = p.Sp[(size_t)m*128 + t]; mmv = p.Mp[(size_t)m*128 + t]; }
        for (int o = 32; o; o >>= 1){ s += __shfl_down(s,o); mmv += __shfl_down(mmv,o); }
        if (t == 0){ smem[0] = s; smem[2] = mmv; }
        if (t == 64){ smem[1] = s; smem[3] = mmv; }
        __syncthreads();
        float Sv = smem[0]+smem[1], Mv = smem[2]+smem[3];
        float rS = 1.f/Sv;
        float2 acc; acc.x = 0.f; acc.y = 0.f;
        const float* base = p.Uwp + (size_t)m*32*DD + 2*t;
#pragma unroll 8
        for (int ch = 0; ch < 32; ch++){
            float2 u = *(const float2*)(base + (size_t)ch*DD);
            acc.x += u.x; acc.y += u.y;
        }
        float2 gvv = ((const float2*)p.gv)[t];
        float2 bvv = ((const float2*)p.bv)[t];
        float2 o2;
        o2.x = gvv.x*(acc.x - Mv)*rS + bvv.x;
        o2.y = gvv.y*(acc.y - Mv)*rS + bvv.y;
        *(float2*)(p.upd + (size_t)m*DD + 2*t) = o2;
    } break;

    case 6: { // GRU gate matmuls: 32 cc x 16 mg, 4 m/wave
        int cc = bx & 31, mg = bx >> 5;
        int c = cc*64 + lane;                     // 0..2047
        int m0 = mg*16 + wv*4;
        int type = c >> 9;
        const f4* x4 = (const f4*)p.upd;
        const f4* h4 = (const f4*)p.slots;
        float acc[4] = {0,0,0,0};
        float bias;
        if (type <= 1){
            const f4* wi = (const f4*)(p.Wih + (size_t)c*DD);
            const f4* wh = (const f4*)(p.Whh + (size_t)c*DD);
            for (int k = 0; k < 128; k++){
                f4 a = wi[k], b4 = wh[k];
#pragma unroll
                for (int mm = 0; mm < 4; mm++)
                    acc[mm] += dot4f(a, x4[(size_t)(m0+mm)*128+k]) + dot4f(b4, h4[(size_t)(m0+mm)*128+k]);
            }
            bias = p.bih[c] + p.bhh[c];
        } else if (type == 2){
            const f4* wi = (const f4*)(p.Wih + (size_t)c*DD);
            for (int k = 0; k < 128; k++){
                f4 a = wi[k];
#pragma unroll
                for (int mm = 0; mm < 4; mm++)
                    acc[mm] += dot4f(a, x4[(size_t)(m0+mm)*128+k]);
            }
            bias = p.bih[c];
        } else {
            int cr = c - 512;
            const f4* wh = (const f4*)(p.Whh + (size_t)cr*DD);
            for (int k = 0; k < 128; k++){
                f4 a = wh[k];
#pragma unroll
                for (int mm = 0; mm < 4; mm++)
                    acc[mm] += dot4f(a, h4[(size_t)(m0+mm)*128+k]);
            }
            bias = p.bhh[cr];
        }
#pragma unroll
        for (int mm = 0; mm < 4; mm++)
            p.gp[(size_t)(m0+mm)*2048 + c] = acc[mm] + bias;
    } break;

    case 7: { // GRU elementwise + LN(gff,bff) fused  (row = bx < 256)
        int m = bx; if (m >= 256) break;
        const float* g = p.gp + (size_t)m*2048;
        float2 rp = *(const float2*)(g + 2*t);
        float2 zp = *(const float2*)(g + 512 + 2*t);
        float2 nx = *(const float2*)(g + 1024 + 2*t);
        float2 nh = *(const float2*)(g + 1536 + 2*t);
        float2 h  = *(const float2*)(p.slots + (size_t)m*DD + 2*t);
        float2 s2;
        {
            float r = 1.f/(1.f + __expf(-rp.x));
            float z = 1.f/(1.f + __expf(-zp.x));
            float n = tanhf(nx.x + r*nh.x);
            s2.x = (1.f - z)*n + z*h.x;
            r = 1.f/(1.f + __expf(-rp.y));
            z = 1.f/(1.f + __expf(-zp.y));
            n = tanhf(nx.y + r*nh.y);
            s2.y = (1.f - z)*n + z*h.y;
        }
        *(float2*)(p.slots2 + (size_t)m*DD + 2*t) = s2;
        float s = s2.x + s2.y;
        float ss = s2.x*s2.x + s2.y*s2.y;
        for (int o = 32; o; o >>= 1){ s += __shfl_down(s,o); ss += __shfl_down(ss,o); }
        if (lane == 0){ smem[wv] = s; smem[4+wv] = ss; }
        __syncthreads();
        float S = smem[0]+smem[1]+smem[2]+smem[3];
        float SS = smem[4]+smem[5]+smem[6]+smem[7];
        float mu = S*(1.f/DD);
        float rstd = rsqrtf(SS*(1.f/DD) - mu*mu + LN_EPS_F);
        float2 gg = *(const float2*)(p.gff + 2*t);
        float2 bb = *(const float2*)(p.bff + 2*t);
        float2 o2;
        o2.x = (s2.x-mu)*rstd*gg.x + bb.x;
        o2.y = (s2.y-mu)*rstd*gg.y + bb.y;
        *(float2*)(p.sbuf + (size_t)m*DD + 2*t) = o2;
    } break;

    case 8: { // FFN1: hid = relu(sbuf@W1^T + b1). 1 row/wave.
        int cc = bx & 7, mg = bx >> 3;
        int c = cc*64 + lane;
        int m = mg*4 + wv;
        const f4* w4 = (const f4*)(p.W1 + (size_t)c*DD);
        const f4* a4 = (const f4*)(p.sbuf + (size_t)m*DD);
        float a0 = 0.f;
        for (int k = 0; k < 128; k++) a0 += dot4f(a4[k], w4[k]);
        p.hid[(size_t)m*DD + c] = fmaxf(a0 + p.b1[c], 0.f);
    } break;

    case 9: { // FFN2: slots = slots2 + hid@W2^T + b2  (+out on last iter)
        int cc = bx & 7, mg = bx >> 3;
        int d = cc*64 + lane;
        int m = mg*4 + wv;
        const f4* w4 = (const f4*)(p.W2 + (size_t)d*DD);
        const f4* h4 = (const f4*)(p.hid + (size_t)m*DD);
        float a0 = 0.f;
        for (int k = 0; k < 128; k++) a0 += dot4f(h4[k], w4[k]);
        float v0 = p.slots2[(size_t)m*DD + d] + a0 + p.b2[d];
        p.slots[(size_t)m*DD + d] = v0;
        if (it == 2) p.out_slots[(size_t)m*DD + d] = v0;
    } break;

    case 10: { // features pf/sf/sf2
        const float2* p2 = (const float2*)p.prompts;
        float2 pr[NSL];
#pragma unroll
        for (int i = 0; i < NSL; i++) pr[i] = p2[i*256 + t];
        for (int vb = bx; vb < 2048; vb += NBLK){
            int b = vb >> 7, pc = (vb & 127)*32;
            __syncthreads();
            for (int idx = t; idx < NSL*32; idx += 256){
                int i = idx >> 5, pp = idx & 31;
                smem[i*33 + pp] = p.out_attn[((size_t)b*NSL + i)*NN + pc + pp];
            }
            float2 sl[NSL];
            const float2* s2 = (const float2*)(p.slots + (size_t)b*NSL*DD);
#pragma unroll
            for (int i = 0; i < NSL; i++) sl[i] = s2[i*256 + t];
            __syncthreads();
            for (int pp = 0; pp < 32; pp++){
                float a0=0.f, a1=0.f, c0=0.f, c1=0.f;
#pragma unroll
                for (int i = 0; i < NSL; i++){
                    float a = smem[i*33 + pp];
                    a0 += a*pr[i].x; a1 += a*pr[i].y;
                    c0 += a*sl[i].x; c1 += a*sl[i].y;
                }
                size_t o = ((size_t)b*NN + pc + pp)*DD + 2*t;
                float2 pv; pv.x=a0; pv.y=a1;
                float2 sv; sv.x=c0; sv.y=c1;
                *(float2*)(p.pf + o)  = pv;
                *(float2*)(p.sf + o)  = sv;
                *(float2*)(p.sf2 + o) = sv;
            }
        }
    } break;
    }
}

__global__ __launch_bounds__(256, 2) void mega_coop(Params p){
    cg::grid_group grid = cg::this_grid();
    run_phase(p, 0, 0); grid.sync();
    for (int it = 0; it < 3; it++){
        for (int ph = 1; ph <= 9; ph++){
            run_phase(p, ph, it);
            grid.sync();
        }
    }
    run_phase(p, 10, 0);
}

__global__ __launch_bounds__(256, 2) void mega_phase(Params p, int phase, int it){
    run_phase(p, phase, it);
}

extern "C" void kernel_launch(void* const* d_in, const int* in_sizes, int n_in,
                              void* d_out, int out_size, void* d_ws, size_t ws_size,
                              hipStream_t stream) {
    Params hp;
    hp.kin     = (const float*)d_in[2];
    hp.vin     = (const float*)d_in[3];
    hp.mu      = (const float*)d_in[4];
    hp.prompts = (const float*)d_in[5];
    hp.Wq  = (const float*)d_in[6];
    hp.bq  = (const float*)d_in[7];
    hp.Wih = (const float*)d_in[8];
    hp.bih = (const float*)d_in[9];
    hp.Whh = (const float*)d_in[10];
    hp.bhh = (const float*)d_in[11];
    hp.W1  = (const float*)d_in[12];
    hp.b1  = (const float*)d_in[13];
    hp.W2  = (const float*)d_in[14];
    hp.b2  = (const float*)d_in[15];
    hp.gk  = (const float*)d_in[16];
    hp.bk  = (const float*)d_in[17];
    hp.gv  = (const float*)d_in[18];
    hp.bv  = (const float*)d_in[19];
    hp.gs  = (const float*)d_in[20];
    hp.bs  = (const float*)d_in[21];
    hp.gff = (const float*)d_in[22];
    hp.bff = (const float*)d_in[23];

    float* ws = (float*)d_ws;
    hp.slots  = ws + 0;
    hp.slots2 = ws + 131072;
    hp.sbuf   = ws + 262144;
    hp.qg     = ws + 393216;
    hp.upd    = ws + 524288;
    hp.hid    = ws + 655360;
    hp.gp     = ws + 786432;
    hp.w      = ws + 1310720;
    hp.vmu    = ws + 2359296;
    hp.vrstd  = ws + 2424832;
    hp.kmu    = ws + 2490368;
    hp.krstd  = ws + 2555904;
    hp.C1p    = ws + 2621440;
    hp.C2p    = ws + 2623488;
    hp.Sp     = ws + 2625536;
    hp.Mp     = ws + 2658304;   // ends at 2691072 floats = 10.8 MB

    float* out   = (float*)d_out;
    hp.out_slots = out;
    hp.out_attn  = out + 131072;
    hp.pf        = out + 1179648;
    hp.sf        = hp.pf + 33554432;
    hp.sf2       = hp.sf + 33554432;
    hp.Uwp       = hp.pf;       // scratch in pf region; overwritten by phase 10

    void* args[] = { &hp };
    hipError_t err = hipLaunchCooperativeKernel((const void*)mega_coop,
                                                dim3(NBLK), dim3(256), args, 0u, stream);
    if (err != hipSuccess){
        (void)hipGetLastError();   // clear; fallback: phase-per-kernel launches
        mega_phase<<<NBLK, 256, 0, stream>>>(hp, 0, 0);
        for (int it = 0; it < 3; it++)
            for (int ph = 1; ph <= 9; ph++)
                mega_phase<<<NBLK, 256, 0, stream>>>(hp, ph, it);
        mega_phase<<<NBLK, 256, 0, stream>>>(hp, 10, 0);
    }
}

// Round 5
// 1225.754 us; speedup vs baseline: 2.5634x; 2.5634x over previous
//
#include <hip/hip_runtime.h>
#include <math.h>

#define NN 4096
#define DD 512
#define NSL 16
#define NBATCH 16
#define SCALE_F 0.044194173824159216f
#define LN_EPS_F 1e-5f
#define ATTN_EPS_F 1e-8f

typedef float4 f4;

__device__ __forceinline__ float dot4f(f4 a, f4 b){
    return a.x*b.x + a.y*b.y + a.z*b.z + a.w*b.w;
}

// ---------------- broadcast slots_mu -> slots ----------------
__global__ __launch_bounds__(256) void k_bcast(const float* __restrict__ mu, float* __restrict__ slots){
    int idx = blockIdx.x*256 + threadIdx.x;           // 32768 f4
    ((f4*)slots)[idx] = ((const f4*)mu)[idx & 2047];
}

// ---------------- fused LN(slots) + q-projection ----------------
// grid (8 c-chunks, 64 m-groups). wave -> one slot row m.
__global__ __launch_bounds__(256) void k_ln_q(const float* __restrict__ slots,
        const float* __restrict__ gs, const float* __restrict__ bs,
        const float* __restrict__ Wq, const float* __restrict__ bq,
        const float* __restrict__ gk, const float* __restrict__ bk,
        float* __restrict__ qg, float* __restrict__ C1p, float* __restrict__ C2p){
    __shared__ __align__(16) float rowL[4*DD];        // 8 KB, per-wave slice
    int lane = threadIdx.x & 63, wv = threadIdx.x >> 6;
    int m = blockIdx.y*4 + wv;                        // 0..255
    int c = blockIdx.x*64 + lane;
    // LN of row m (each lane holds 8 elems)
    const f4* r4 = (const f4*)(slots + (size_t)m*DD);
    f4 v0 = r4[lane*2], v1 = r4[lane*2+1];
    float s  = v0.x+v0.y+v0.z+v0.w + v1.x+v1.y+v1.z+v1.w;
    float ss = v0.x*v0.x+v0.y*v0.y+v0.z*v0.z+v0.w*v0.w
             + v1.x*v1.x+v1.y*v1.y+v1.z*v1.z+v1.w*v1.w;
    for (int o = 32; o; o >>= 1){ s += __shfl_down(s,o); ss += __shfl_down(ss,o); }
    s = __shfl(s,0); ss = __shfl(ss,0);
    float mu = s*(1.f/DD);
    float rstd = rsqrtf(ss*(1.f/DD) - mu*mu + LN_EPS_F);
    const f4* g4 = (const f4*)gs; const f4* b4 = (const f4*)bs;
    f4 g0 = g4[lane*2], g1 = g4[lane*2+1], c0 = b4[lane*2], c1 = b4[lane*2+1];
    f4 o0, o1;
    o0.x=(v0.x-mu)*rstd*g0.x+c0.x; o0.y=(v0.y-mu)*rstd*g0.y+c0.y;
    o0.z=(v0.z-mu)*rstd*g0.z+c0.z; o0.w=(v0.w-mu)*rstd*g0.w+c0.w;
    o1.x=(v1.x-mu)*rstd*g1.x+c1.x; o1.y=(v1.y-mu)*rstd*g1.y+c1.y;
    o1.z=(v1.z-mu)*rstd*g1.z+c1.z; o1.w=(v1.w-mu)*rstd*g1.w+c1.w;
    f4* rw = (f4*)(rowL + wv*DD);
    rw[lane*2] = o0; rw[lane*2+1] = o1;
    __syncthreads();
    // q[m,c]
    const f4* w4 = (const f4*)(Wq + (size_t)c*DD);
    float acc = 0.f;
    for (int k = 0; k < 128; k++) acc += dot4f(rw[k], w4[k]);
    float q0 = acc + bq[c];
    float qg0 = q0 * gk[c];
    qg[(size_t)m*DD + c] = qg0;
    float r1 = qg0, r2 = q0 * bk[c];
    for (int o = 32; o; o >>= 1){ r1 += __shfl_down(r1,o); r2 += __shfl_down(r2,o); }
    if (lane == 0){
        C1p[blockIdx.x*256 + m] = r1;
        C2p[blockIdx.x*256 + m] = r2;
    }
}

// ---------------- fused QK^T + inverted softmax + AV partial ----------------
// grid (32 j-chunks of 128, 16 b). waves 0,1: k rows; waves 2,3: v stats.
__global__ __launch_bounds__(256, 2) void k_attn_av(const float* __restrict__ kin,
        const float* __restrict__ vin, const float* __restrict__ qg,
        const float* __restrict__ C1p, const float* __restrict__ C2p,
        float* __restrict__ Sp, float* __restrict__ Mp, float* __restrict__ Uwp,
        float* __restrict__ attn_out, int last){
    __shared__ __align__(16) f4 qgL[NSL*128];         // 32 KB
    __shared__ __align__(16) float wL[128*20];        // 10 KB
    __shared__ float vmuL[128], vrsL[128];
    __shared__ float c1s[NSL], c2s[NSL];
    __shared__ float spL[2][NSL], mpL[2][NSL];
    int chunk = blockIdx.x, b = blockIdx.y;
    int t = threadIdx.x, lane = t & 63, wv = t >> 6;

    const f4* qgg = (const f4*)(qg + (size_t)b*NSL*DD);
    for (int idx = t; idx < NSL*128; idx += 256) qgL[idx] = qgg[idx];
    if (t < NSL){
        float c1 = 0.f, c2 = 0.f;
#pragma unroll
        for (int k = 0; k < 8; k++){
            c1 += C1p[k*256 + b*NSL + t];
            c2 += C2p[k*256 + b*NSL + t];
        }
        c1s[t] = c1; c2s[t] = c2;
    }
    __syncthreads();

    float a[NSL];
    if (t < 128){
        // k-row j: stats + 16 dots + in-register softmax over slots
        int j = chunk*128 + t;
        const f4* kr = (const f4*)(kin + ((size_t)b*NN + j)*DD);
        float acc[NSL];
#pragma unroll
        for (int i = 0; i < NSL; i++) acc[i] = 0.f;
        float s = 0.f, ss = 0.f;
        for (int dd = 0; dd < 128; dd++){
            f4 kv = kr[dd];
            s  += kv.x+kv.y+kv.z+kv.w;
            ss += kv.x*kv.x+kv.y*kv.y+kv.z*kv.z+kv.w*kv.w;
#pragma unroll
            for (int i = 0; i < NSL; i++) acc[i] += dot4f(qgL[i*128+dd], kv);
        }
        float mu = s*(1.f/DD);
        float rstd = rsqrtf(ss*(1.f/DD) - mu*mu + LN_EPS_F);
        float mx = -1e30f;
#pragma unroll
        for (int i = 0; i < NSL; i++){
            a[i] = SCALE_F*(rstd*(acc[i] - mu*c1s[i]) + c2s[i]);
            mx = fmaxf(mx, a[i]);
        }
        float se = 0.f;
#pragma unroll
        for (int i = 0; i < NSL; i++){ a[i] = __expf(a[i]-mx); se += a[i]; }
        float inv = 1.f/se;
#pragma unroll
        for (int i = 0; i < NSL; i++) a[i] = a[i]*inv + ATTN_EPS_F;
    } else {
        // v-row stats for j = chunk*128 + (t-128)
        int jv = t - 128;
        int j = chunk*128 + jv;
        const f4* vr = (const f4*)(vin + ((size_t)b*NN + j)*DD);
        float s = 0.f, ss = 0.f;
        for (int dd = 0; dd < 128; dd++){
            f4 vv = vr[dd];
            s  += vv.x+vv.y+vv.z+vv.w;
            ss += vv.x*vv.x+vv.y*vv.y+vv.z*vv.z+vv.w*vv.w;
        }
        float m = s*(1.f/DD);
        vmuL[jv] = m;
        vrsL[jv] = rsqrtf(ss*(1.f/DD) - m*m + LN_EPS_F);
    }
    __syncthreads();

    if (t < 128){
        float rv = vrsL[t], vm = vmuL[t];
        float w16[NSL];
#pragma unroll
        for (int i = 0; i < NSL; i++){
            float wvl = a[i]*rv;
            w16[i] = wvl;
            wL[t*20 + i] = wvl;
        }
        // block partials: Sp_i = sum_j a ; Mp_i = sum_j w*vmu
#pragma unroll
        for (int i = 0; i < NSL; i++){
            float r1 = a[i], r2 = w16[i]*vm;
            for (int o = 32; o; o >>= 1){ r1 += __shfl_down(r1,o); r2 += __shfl_down(r2,o); }
            if (lane == 0){ spL[wv][i] = r1; mpL[wv][i] = r2; }
        }
        if (last){
            int j = chunk*128 + t;
#pragma unroll
            for (int i = 0; i < NSL; i++)
                attn_out[((size_t)b*NSL + i)*NN + j] = a[i];
        }
    }
    __syncthreads();

    if (t < NSL)
        Sp[((size_t)b*NSL + t)*32 + chunk] = spL[0][t] + spL[1][t];
    else if (t < 2*NSL)
        Mp[((size_t)b*NSL + (t-NSL))*32 + chunk] = mpL[0][t-NSL] + mpL[1][t-NSL];

    // AV partial: thread owns d-pair (2t, 2t+1), loops the 128 j's
    f4 ax[4], ay[4];
#pragma unroll
    for (int g2 = 0; g2 < 4; g2++){ ax[g2] = f4{0,0,0,0}; ay[g2] = f4{0,0,0,0}; }
    const float2* v2 = (const float2*)(vin + ((size_t)b*NN + (size_t)chunk*128)*DD);
#pragma unroll 2
    for (int jj = 0; jj < 128; jj++){
        float2 vv = v2[(size_t)jj*256 + t];
        const f4* wl4 = (const f4*)(wL + jj*20);
#pragma unroll
        for (int g2 = 0; g2 < 4; g2++){
            f4 wq = wl4[g2];
            ax[g2].x += wq.x*vv.x; ax[g2].y += wq.y*vv.x; ax[g2].z += wq.z*vv.x; ax[g2].w += wq.w*vv.x;
            ay[g2].x += wq.x*vv.y; ay[g2].y += wq.y*vv.y; ay[g2].z += wq.z*vv.y; ay[g2].w += wq.w*vv.y;
        }
    }
#pragma unroll
    for (int g2 = 0; g2 < 4; g2++){
        const float* px = (const float*)&ax[g2];
        const float* py = (const float*)&ay[g2];
#pragma unroll
        for (int c4 = 0; c4 < 4; c4++){
            int i = g2*4 + c4;
            float2 o2; o2.x = px[c4]; o2.y = py[c4];
            *(float2*)(Uwp + (((size_t)(b*NSL + i))*32 + chunk)*DD + 2*t) = o2;
        }
    }
}

// ---------------- updates = gv*(sum Uwp - M)/S + bv  (block = row m) ----------------
__global__ __launch_bounds__(256) void k_upd(const float* __restrict__ Uwp,
        const float* __restrict__ Sp, const float* __restrict__ Mp,
        const float* __restrict__ gv, const float* __restrict__ bv,
        float* __restrict__ upd){
    __shared__ float sm[2];
    int m = blockIdx.x, t = threadIdx.x, lane = t & 63;
    if (t < 64){
        float val = (lane < 32) ? Sp[(size_t)m*32 + lane] : Mp[(size_t)m*32 + lane - 32];
        for (int o = 16; o; o >>= 1) val += __shfl_xor(val, o);
        if (lane == 0) sm[0] = val;
        if (lane == 32) sm[1] = val;
    }
    __syncthreads();
    float Sv = sm[0], Mv = sm[1];
    float rS = 1.f/Sv;
    float2 acc; acc.x = 0.f; acc.y = 0.f;
    const float* base = Uwp + (size_t)m*32*DD + 2*t;
#pragma unroll 8
    for (int ch = 0; ch < 32; ch++){
        float2 u = *(const float2*)(base + (size_t)ch*DD);
        acc.x += u.x; acc.y += u.y;
    }
    float2 gvv = ((const float2*)gv)[t];
    float2 bvv = ((const float2*)bv)[t];
    float2 o2;
    o2.x = gvv.x*(acc.x - Mv)*rS + bvv.x;
    o2.y = gvv.y*(acc.y - Mv)*rS + bvv.y;
    *(float2*)(upd + (size_t)m*DD + 2*t) = o2;
}

// ---------------- GRU gate matmuls: grid (32 cc, 16 mg), 4 m/wave ----------------
__global__ __launch_bounds__(256) void k_gru_mm(const float* __restrict__ x, const float* __restrict__ h,
        const float* __restrict__ Wih, const float* __restrict__ bih,
        const float* __restrict__ Whh, const float* __restrict__ bhh,
        float* __restrict__ gp){
    int lane = threadIdx.x & 63, wv = threadIdx.x >> 6;
    int c = blockIdx.x*64 + lane;                 // 0..2047
    int m0 = blockIdx.y*16 + wv*4;
    int type = c >> 9;
    const f4* x4 = (const f4*)x;
    const f4* h4 = (const f4*)h;
    float acc[4] = {0,0,0,0};
    float bias;
    if (type <= 1){
        const f4* wi = (const f4*)(Wih + (size_t)c*DD);
        const f4* wh = (const f4*)(Whh + (size_t)c*DD);
        for (int k = 0; k < 128; k++){
            f4 aa = wi[k], bb = wh[k];
#pragma unroll
            for (int mm = 0; mm < 4; mm++)
                acc[mm] += dot4f(aa, x4[(size_t)(m0+mm)*128+k]) + dot4f(bb, h4[(size_t)(m0+mm)*128+k]);
        }
        bias = bih[c] + bhh[c];
    } else if (type == 2){
        const f4* wi = (const f4*)(Wih + (size_t)c*DD);
        for (int k = 0; k < 128; k++){
            f4 aa = wi[k];
#pragma unroll
            for (int mm = 0; mm < 4; mm++)
                acc[mm] += dot4f(aa, x4[(size_t)(m0+mm)*128+k]);
        }
        bias = bih[c];
    } else {
        int cr = c - 512;
        const f4* wh = (const f4*)(Whh + (size_t)cr*DD);
        for (int k = 0; k < 128; k++){
            f4 aa = wh[k];
#pragma unroll
            for (int mm = 0; mm < 4; mm++)
                acc[mm] += dot4f(aa, h4[(size_t)(m0+mm)*128+k]);
        }
        bias = bhh[cr];
    }
#pragma unroll
    for (int mm = 0; mm < 4; mm++)
        gp[(size_t)(m0+mm)*2048 + c] = acc[mm] + bias;
}

// ---------------- GRU elementwise + LN(gff,bff) fused  (block = row m) ----------------
__global__ __launch_bounds__(256) void k_gru_ln(const float* __restrict__ gp,
        const float* __restrict__ h, const float* __restrict__ gff, const float* __restrict__ bff,
        float* __restrict__ slots2, float* __restrict__ sbuf){
    __shared__ float sm[8];
    int m = blockIdx.x, t = threadIdx.x, lane = t & 63, wv = t >> 6;
    const float* g = gp + (size_t)m*2048;
    float2 rp = *(const float2*)(g + 2*t);
    float2 zp = *(const float2*)(g + 512 + 2*t);
    float2 nx = *(const float2*)(g + 1024 + 2*t);
    float2 nh = *(const float2*)(g + 1536 + 2*t);
    float2 hh = *(const float2*)(h + (size_t)m*DD + 2*t);
    float2 s2;
    {
        float r = 1.f/(1.f + __expf(-rp.x));
        float z = 1.f/(1.f + __expf(-zp.x));
        float n = tanhf(nx.x + r*nh.x);
        s2.x = (1.f - z)*n + z*hh.x;
        r = 1.f/(1.f + __expf(-rp.y));
        z = 1.f/(1.f + __expf(-zp.y));
        n = tanhf(nx.y + r*nh.y);
        s2.y = (1.f - z)*n + z*hh.y;
    }
    *(float2*)(slots2 + (size_t)m*DD + 2*t) = s2;
    float s = s2.x + s2.y;
    float ss = s2.x*s2.x + s2.y*s2.y;
    for (int o = 32; o; o >>= 1){ s += __shfl_down(s,o); ss += __shfl_down(ss,o); }
    if (lane == 0){ sm[wv] = s; sm[4+wv] = ss; }
    __syncthreads();
    float S = sm[0]+sm[1]+sm[2]+sm[3];
    float SS = sm[4]+sm[5]+sm[6]+sm[7];
    float mu = S*(1.f/DD);
    float rstd = rsqrtf(SS*(1.f/DD) - mu*mu + LN_EPS_F);
    float2 gg = *(const float2*)(gff + 2*t);
    float2 bb = *(const float2*)(bff + 2*t);
    float2 o2;
    o2.x = (s2.x-mu)*rstd*gg.x + bb.x;
    o2.y = (s2.y-mu)*rstd*gg.y + bb.y;
    *(float2*)(sbuf + (size_t)m*DD + 2*t) = o2;
}

// ---------------- FFN1: hid = relu(sbuf@W1^T + b1) ----------------
__global__ __launch_bounds__(256) void k_ffn1(const float* __restrict__ a, const float* __restrict__ W1,
                                              const float* __restrict__ b1, float* __restrict__ hid){
    int lane = threadIdx.x & 63, wv = threadIdx.x >> 6;
    int c = blockIdx.x*64 + lane;
    int m0 = blockIdx.y*16 + wv*4;
    const f4* w4 = (const f4*)(W1 + (size_t)c*DD);
    const f4* a4 = (const f4*)a;
    float acc[4] = {0,0,0,0};
    for (int k = 0; k < 128; k++){
        f4 w = w4[k];
#pragma unroll
        for (int mm = 0; mm < 4; mm++)
            acc[mm] += dot4f(w, a4[(size_t)(m0+mm)*128+k]);
    }
    float bc = b1[c];
#pragma unroll
    for (int mm = 0; mm < 4; mm++)
        hid[(size_t)(m0+mm)*DD + c] = fmaxf(acc[mm] + bc, 0.f);
}

// ---------------- FFN2: slots = slots2 + hid@W2^T + b2 (+out last iter) ----------------
__global__ __launch_bounds__(256) void k_ffn2(const float* __restrict__ hid, const float* __restrict__ W2,
                                              const float* __restrict__ b2, const float* __restrict__ slots2,
                                              float* __restrict__ slots, float* __restrict__ out_slots, int last){
    int lane = threadIdx.x & 63, wv = threadIdx.x >> 6;
    int d = blockIdx.x*64 + lane;
    int m0 = blockIdx.y*16 + wv*4;
    const f4* w4 = (const f4*)(W2 + (size_t)d*DD);
    const f4* h4 = (const f4*)hid;
    float acc[4] = {0,0,0,0};
    for (int k = 0; k < 128; k++){
        f4 w = w4[k];
#pragma unroll
        for (int mm = 0; mm < 4; mm++)
            acc[mm] += dot4f(w, h4[(size_t)(m0+mm)*128+k]);
    }
    float bc = b2[d];
#pragma unroll
    for (int mm = 0; mm < 4; mm++){
        float v0 = slots2[(size_t)(m0+mm)*DD + d] + acc[mm] + bc;
        slots[(size_t)(m0+mm)*DD + d] = v0;
        if (last) out_slots[(size_t)(m0+mm)*DD + d] = v0;
    }
}

// ---------------- features: pf/sf/sf2 ----------------
__global__ __launch_bounds__(256) void k_features(const float* __restrict__ prompts, const float* __restrict__ slots,
        const float* __restrict__ attn, float* __restrict__ pf, float* __restrict__ sf, float* __restrict__ sf2){
    int b = blockIdx.y;
    int pbase = blockIdx.x*32;
    int t = threadIdx.x;
    __shared__ float al[NSL][33];
    for (int idx = t; idx < NSL*32; idx += 256){
        int i = idx >> 5, pp = idx & 31;
        al[i][pp] = attn[((size_t)b*NSL + i)*NN + pbase + pp];
    }
    float2 pr[NSL], sl[NSL];
    const float2* p2 = (const float2*)prompts;
    const float2* s2 = (const float2*)(slots + (size_t)b*NSL*DD);
#pragma unroll
    for (int i = 0; i < NSL; i++){ pr[i] = p2[i*256+t]; sl[i] = s2[i*256+t]; }
    __syncthreads();
    for (int pp = 0; pp < 32; pp++){
        float a0=0.f, a1=0.f, c0=0.f, c1=0.f;
#pragma unroll
        for (int i = 0; i < NSL; i++){
            float a = al[i][pp];
            a0 += a*pr[i].x; a1 += a*pr[i].y;
            c0 += a*sl[i].x; c1 += a*sl[i].y;
        }
        size_t o = ((size_t)b*NN + pbase + pp)*DD + 2*t;
        float2 pv; pv.x=a0; pv.y=a1;
        float2 sv; sv.x=c0; sv.y=c1;
        *(float2*)(pf + o)  = pv;
        *(float2*)(sf + o)  = sv;
        *(float2*)(sf2 + o) = sv;
    }
}

extern "C" void kernel_launch(void* const* d_in, const int* in_sizes, int n_in,
                              void* d_out, int out_size, void* d_ws, size_t ws_size,
                              hipStream_t stream) {
    const float* k_inp   = (const float*)d_in[2];
    const float* v_inp   = (const float*)d_in[3];
    const float* slots_mu= (const float*)d_in[4];
    const float* prompts = (const float*)d_in[5];
    const float* Wq      = (const float*)d_in[6];
    const float* bq      = (const float*)d_in[7];
    const float* W_ih    = (const float*)d_in[8];
    const float* b_ih    = (const float*)d_in[9];
    const float* W_hh    = (const float*)d_in[10];
    const float* b_hh    = (const float*)d_in[11];
    const float* W1      = (const float*)d_in[12];
    const float* b1      = (const float*)d_in[13];
    const float* W2      = (const float*)d_in[14];
    const float* b2      = (const float*)d_in[15];
    const float* gk      = (const float*)d_in[16];
    const float* bk      = (const float*)d_in[17];
    const float* gv      = (const float*)d_in[18];
    const float* bv      = (const float*)d_in[19];
    const float* gs      = (const float*)d_in[20];
    const float* bs      = (const float*)d_in[21];
    const float* gff     = (const float*)d_in[22];
    const float* bff     = (const float*)d_in[23];

    float* ws = (float*)d_ws;
    float* slots   = ws + 0;
    float* slots2  = ws + 131072;
    float* sbuf    = ws + 262144;
    float* qg      = ws + 393216;
    float* upd     = ws + 524288;
    float* hid     = ws + 655360;
    float* gp      = ws + 786432;     // 524288 floats -> ends 1310720
    float* C1p     = ws + 1310720;    // 2048
    float* C2p     = ws + 1312768;    // 2048
    float* Sp      = ws + 1314816;    // 8192
    float* Mp      = ws + 1323008;    // 8192 -> ends 1331200 floats (5.3 MB)

    float* out      = (float*)d_out;
    float* attn_out = out + 131072;
    float* pf       = out + 1179648;
    float* sf       = pf + 33554432;
    float* sf2      = sf + 33554432;
    float* Uwp      = pf;             // 4.2M floats scratch; overwritten by k_features

    k_bcast<<<128, 256, 0, stream>>>(slots_mu, slots);

    for (int it = 0; it < 3; it++){
        int last = (it == 2);
        k_ln_q<<<dim3(8,64), 256, 0, stream>>>(slots, gs, bs, Wq, bq, gk, bk, qg, C1p, C2p);
        k_attn_av<<<dim3(32,16), 256, 0, stream>>>(k_inp, v_inp, qg, C1p, C2p,
                                                   Sp, Mp, Uwp, attn_out, last);
        k_upd<<<256, 256, 0, stream>>>(Uwp, Sp, Mp, gv, bv, upd);
        k_gru_mm<<<dim3(32,16), 256, 0, stream>>>(upd, slots, W_ih, b_ih, W_hh, b_hh, gp);
        k_gru_ln<<<256, 256, 0, stream>>>(gp, slots, gff, bff, slots2, sbuf);
        k_ffn1<<<dim3(8,16), 256, 0, stream>>>(sbuf, W1, b1, hid);
        k_ffn2<<<dim3(8,16), 256, 0, stream>>>(hid, W2, b2, slots2, slots, out, last);
    }

    k_features<<<dim3(128,16), 256, 0, stream>>>(prompts, slots, attn_out, pf, sf, sf2);
}

// Round 7
// 1207.409 us; speedup vs baseline: 2.6023x; 1.0152x over previous
//
#include <hip/hip_runtime.h>
#include <math.h>

#define NN 4096
#define DD 512
#define NSL 16
#define SCALE_F 0.044194173824159216f
#define LN_EPS_F 1e-5f
#define ATTN_EPS_F 1e-8f

typedef float4 f4;
typedef __fp16 h2 __attribute__((ext_vector_type(2)));      // cvt_pkrtz return type
typedef _Float16 h2f __attribute__((ext_vector_type(2)));   // fdot2 operand type

#if defined(__has_builtin)
#if __has_builtin(__builtin_amdgcn_fdot2) && __has_builtin(__builtin_amdgcn_cvt_pkrtz)
#define USE_FDOT2 1
#endif
#endif

__device__ __forceinline__ float dot4f(f4 a, f4 b){
    return a.x*b.x + a.y*b.y + a.z*b.z + a.w*b.w;
}

#ifdef USE_FDOT2
__device__ __forceinline__ float fdot2f(h2 a, h2 b, float c){
    return __builtin_amdgcn_fdot2(__builtin_bit_cast(h2f, a),
                                  __builtin_bit_cast(h2f, b), c, false);
}
__device__ __forceinline__ unsigned pk(float x, float y){
    return __builtin_bit_cast(unsigned, __builtin_amdgcn_cvt_pkrtz(x, y));
}
#endif

// ---- pre: slots bcast + per-row stats of v and k (once; iteration-invariant) ----
__global__ __launch_bounds__(256) void k_pre(const float* __restrict__ mu,
        const float* __restrict__ kin, const float* __restrict__ vin,
        float* __restrict__ slots, float* __restrict__ kmu, float* __restrict__ krstd,
        float* __restrict__ vmu, float* __restrict__ vrstd){
    int idx = blockIdx.x*256 + threadIdx.x;       // 0..131071
    if (idx < 32768) ((f4*)slots)[idx] = ((const f4*)mu)[idx & 2047];
    int half = idx >> 16;                          // 0: v, 1: k
    int row = idx & 65535;
    const float* src = half ? kin : vin;
    const f4* r4 = (const f4*)(src + (size_t)row*DD);
    float s = 0.f, ss = 0.f;
    for (int c = 0; c < 128; c++){
        f4 x = r4[c];
        s  += x.x+x.y+x.z+x.w;
        ss += x.x*x.x+x.y*x.y+x.z*x.z+x.w*x.w;
    }
    float m = s*(1.f/DD);
    float rs = rsqrtf(ss*(1.f/DD) - m*m + LN_EPS_F);
    if (half){ kmu[row] = m; krstd[row] = rs; }
    else     { vmu[row] = m; vrstd[row] = rs; }
}

// ---- fused LN(slots) + q-projection ----
__global__ __launch_bounds__(256) void k_ln_q(const float* __restrict__ slots,
        const float* __restrict__ gs, const float* __restrict__ bs,
        const float* __restrict__ Wq, const float* __restrict__ bq,
        const float* __restrict__ gk, const float* __restrict__ bk,
        float* __restrict__ qg, float* __restrict__ C1p, float* __restrict__ C2p){
    __shared__ __align__(16) float rowL[4*DD];
    int lane = threadIdx.x & 63, wv = threadIdx.x >> 6;
    int m = blockIdx.y*4 + wv;
    int c = blockIdx.x*64 + lane;
    const f4* r4 = (const f4*)(slots + (size_t)m*DD);
    f4 v0 = r4[lane*2], v1 = r4[lane*2+1];
    float s  = v0.x+v0.y+v0.z+v0.w + v1.x+v1.y+v1.z+v1.w;
    float ss = v0.x*v0.x+v0.y*v0.y+v0.z*v0.z+v0.w*v0.w
             + v1.x*v1.x+v1.y*v1.y+v1.z*v1.z+v1.w*v1.w;
    for (int o = 32; o; o >>= 1){ s += __shfl_down(s,o); ss += __shfl_down(ss,o); }
    s = __shfl(s,0); ss = __shfl(ss,0);
    float mu = s*(1.f/DD);
    float rstd = rsqrtf(ss*(1.f/DD) - mu*mu + LN_EPS_F);
    const f4* g4 = (const f4*)gs; const f4* b4 = (const f4*)bs;
    f4 g0 = g4[lane*2], g1 = g4[lane*2+1], c0 = b4[lane*2], c1 = b4[lane*2+1];
    f4 o0, o1;
    o0.x=(v0.x-mu)*rstd*g0.x+c0.x; o0.y=(v0.y-mu)*rstd*g0.y+c0.y;
    o0.z=(v0.z-mu)*rstd*g0.z+c0.z; o0.w=(v0.w-mu)*rstd*g0.w+c0.w;
    o1.x=(v1.x-mu)*rstd*g1.x+c1.x; o1.y=(v1.y-mu)*rstd*g1.y+c1.y;
    o1.z=(v1.z-mu)*rstd*g1.z+c1.z; o1.w=(v1.w-mu)*rstd*g1.w+c1.w;
    f4* rw = (f4*)(rowL + wv*DD);
    rw[lane*2] = o0; rw[lane*2+1] = o1;
    __syncthreads();
    const f4* w4 = (const f4*)(Wq + (size_t)c*DD);
    float acc = 0.f;
    for (int k = 0; k < 128; k++) acc += dot4f(rw[k], w4[k]);
    float q0 = acc + bq[c];
    float qg0 = q0 * gk[c];
    qg[(size_t)m*DD + c] = qg0;
    float r1 = qg0, r2 = q0 * bk[c];
    for (int o = 32; o; o >>= 1){ r1 += __shfl_down(r1,o); r2 += __shfl_down(r2,o); }
    if (lane == 0){
        C1p[blockIdx.x*256 + m] = r1;
        C2p[blockIdx.x*256 + m] = r2;
    }
}

// ---- fused QK^T + inverted softmax + AV partial. grid (16 chunks of 256 j, 16 b) ----
__global__ __launch_bounds__(256) void k_attn_av(const float* __restrict__ kin,
        const float* __restrict__ vin, const float* __restrict__ qg,
        const float* __restrict__ C1p, const float* __restrict__ C2p,
        const float* __restrict__ kmu, const float* __restrict__ krstd,
        const float* __restrict__ vmu, const float* __restrict__ vrstd,
        float* __restrict__ Sp, float* __restrict__ Mp, float* __restrict__ Uwp,
        float* __restrict__ attn_out, int last){
#ifdef USE_FDOT2
    __shared__ __align__(16) uint4 qhL[1024];      // 16 KB packed f16
#else
    __shared__ __align__(16) f4 qgL[2048];         // 32 KB fp32
#endif
    __shared__ __align__(16) float wL[256*20];     // 20 KB
    __shared__ float c1s[NSL], c2s[NSL];
    __shared__ float spL[4][NSL], mpL[4][NSL];
    int chunk = blockIdx.x, b = blockIdx.y;
    int t = threadIdx.x, lane = t & 63, wv = t >> 6;

    const f4* qgg = (const f4*)(qg + (size_t)b*NSL*DD);
#ifdef USE_FDOT2
    for (int e = t; e < 1024; e += 256){
        int dd = e >> 3, p = e & 7;
        f4 qa = qgg[(size_t)(2*p)*128 + dd];
        f4 qb = qgg[(size_t)(2*p+1)*128 + dd];
        uint4 u;
        u.x = pk(qa.x, qa.y);
        u.y = pk(qb.x, qb.y);
        u.z = pk(qa.z, qa.w);
        u.w = pk(qb.z, qb.w);
        qhL[e] = u;
    }
#else
    for (int e = t; e < 2048; e += 256) qgL[e] = qgg[e];
#endif
    if (t < NSL){
        float c1 = 0.f, c2 = 0.f;
#pragma unroll
        for (int k = 0; k < 8; k++){
            c1 += C1p[k*256 + b*NSL + t];
            c2 += C2p[k*256 + b*NSL + t];
        }
        c1s[t] = c1; c2s[t] = c2;
    }
    __syncthreads();

    // ---- QK: thread owns row j ----
    int j = chunk*256 + t;
    const f4* kr = (const f4*)(kin + ((size_t)b*NN + j)*DD);
    float a[NSL];
#pragma unroll
    for (int i = 0; i < NSL; i++) a[i] = 0.f;
    f4 kv = kr[0];
    for (int dd = 0; dd < 128; dd++){
        f4 nk;
        if (dd < 127) nk = kr[dd+1];
#ifdef USE_FDOT2
        h2 k01 = __builtin_amdgcn_cvt_pkrtz(kv.x, kv.y);
        h2 k23 = __builtin_amdgcn_cvt_pkrtz(kv.z, kv.w);
#pragma unroll
        for (int p = 0; p < 8; p++){
            uint4 u = qhL[dd*8 + p];
            h2 q0a = __builtin_bit_cast(h2, u.x);
            h2 q1a = __builtin_bit_cast(h2, u.y);
            h2 q0b = __builtin_bit_cast(h2, u.z);
            h2 q1b = __builtin_bit_cast(h2, u.w);
            a[2*p]   = fdot2f(k01, q0a, a[2*p]);
            a[2*p]   = fdot2f(k23, q0b, a[2*p]);
            a[2*p+1] = fdot2f(k01, q1a, a[2*p+1]);
            a[2*p+1] = fdot2f(k23, q1b, a[2*p+1]);
        }
#else
#pragma unroll
        for (int i = 0; i < NSL; i++) a[i] += dot4f(qgL[i*128+dd], kv);
#endif
        kv = nk;
    }
    float mu = kmu[(size_t)b*NN + j];
    float rstd = krstd[(size_t)b*NN + j];
    float mx = -1e30f;
#pragma unroll
    for (int i = 0; i < NSL; i++){
        a[i] = SCALE_F*(rstd*(a[i] - mu*c1s[i]) + c2s[i]);
        mx = fmaxf(mx, a[i]);
    }
    float se = 0.f;
#pragma unroll
    for (int i = 0; i < NSL; i++){ a[i] = __expf(a[i]-mx); se += a[i]; }
    float inv = 1.f/se;
    float rv = vrstd[(size_t)b*NN + j];
    float vm = vmu[(size_t)b*NN + j];
#pragma unroll
    for (int i = 0; i < NSL; i++){
        a[i] = a[i]*inv + ATTN_EPS_F;
        wL[t*20 + i] = a[i]*rv;
    }
#pragma unroll
    for (int i = 0; i < NSL; i++){
        float r1 = a[i], r2 = a[i]*rv*vm;
        for (int o = 32; o; o >>= 1){ r1 += __shfl_down(r1,o); r2 += __shfl_down(r2,o); }
        if (lane == 0){ spL[wv][i] = r1; mpL[wv][i] = r2; }
    }
    if (last){
#pragma unroll
        for (int i = 0; i < NSL; i++)
            attn_out[((size_t)b*NSL + i)*NN + j] = a[i];
    }
    __syncthreads();

    if (t < NSL)
        Sp[((size_t)b*NSL + t)*16 + chunk] = spL[0][t]+spL[1][t]+spL[2][t]+spL[3][t];
    else if (t < 2*NSL){
        int i = t - NSL;
        Mp[((size_t)b*NSL + i)*16 + chunk] = mpL[0][i]+mpL[1][i]+mpL[2][i]+mpL[3][i];
    }

    // ---- AV partial over this chunk's 256 j ----
    f4 ax[4], ay[4];
#pragma unroll
    for (int g2 = 0; g2 < 4; g2++){ ax[g2] = f4{0,0,0,0}; ay[g2] = f4{0,0,0,0}; }
    const float2* v2 = (const float2*)(vin + ((size_t)b*NN + (size_t)chunk*256)*DD);
#pragma unroll 2
    for (int jj = 0; jj < 256; jj++){
        float2 vv = v2[(size_t)jj*256 + t];
        const f4* wl4 = (const f4*)(wL + jj*20);
#pragma unroll
        for (int g2 = 0; g2 < 4; g2++){
            f4 wq = wl4[g2];
            ax[g2].x += wq.x*vv.x; ax[g2].y += wq.y*vv.x; ax[g2].z += wq.z*vv.x; ax[g2].w += wq.w*vv.x;
            ay[g2].x += wq.x*vv.y; ay[g2].y += wq.y*vv.y; ay[g2].z += wq.z*vv.y; ay[g2].w += wq.w*vv.y;
        }
    }
#pragma unroll
    for (int g2 = 0; g2 < 4; g2++){
        const float* px = (const float*)&ax[g2];
        const float* py = (const float*)&ay[g2];
#pragma unroll
        for (int c4 = 0; c4 < 4; c4++){
            int i = g2*4 + c4;
            float2 o2; o2.x = px[c4]; o2.y = py[c4];
            *(float2*)(Uwp + (((size_t)(b*NSL + i))*16 + chunk)*DD + 2*t) = o2;
        }
    }
}

// ---- updates = gv*(sum Uwp - M)/S + bv  (block = row m) ----
__global__ __launch_bounds__(256) void k_upd(const float* __restrict__ Uwp,
        const float* __restrict__ Sp, const float* __restrict__ Mp,
        const float* __restrict__ gv, const float* __restrict__ bv,
        float* __restrict__ upd){
    __shared__ float sm[2];
    int m = blockIdx.x, t = threadIdx.x;
    if (t < 32){
        float val = (t < 16) ? Sp[(size_t)m*16 + (t&15)] : Mp[(size_t)m*16 + (t&15)];
        val += __shfl_xor(val, 1);
        val += __shfl_xor(val, 2);
        val += __shfl_xor(val, 4);
        val += __shfl_xor(val, 8);
        if (t == 0)  sm[0] = val;
        if (t == 16) sm[1] = val;
    }
    __syncthreads();
    float Sv = sm[0], Mv = sm[1];
    float rS = 1.f/Sv;
    float2 acc; acc.x = 0.f; acc.y = 0.f;
    const float* base = Uwp + (size_t)m*16*DD + 2*t;
#pragma unroll
    for (int ch = 0; ch < 16; ch++){
        float2 u = *(const float2*)(base + (size_t)ch*DD);
        acc.x += u.x; acc.y += u.y;
    }
    float2 gvv = ((const float2*)gv)[t];
    float2 bvv = ((const float2*)bv)[t];
    float2 o2;
    o2.x = gvv.x*(acc.x - Mv)*rS + bvv.x;
    o2.y = gvv.y*(acc.y - Mv)*rS + bvv.y;
    *(float2*)(upd + (size_t)m*DD + 2*t) = o2;
}

// ---- GRU gate matmuls ----
__global__ __launch_bounds__(256) void k_gru_mm(const float* __restrict__ x, const float* __restrict__ h,
        const float* __restrict__ Wih, const float* __restrict__ bih,
        const float* __restrict__ Whh, const float* __restrict__ bhh,
        float* __restrict__ gp){
    int lane = threadIdx.x & 63, wv = threadIdx.x >> 6;
    int c = blockIdx.x*64 + lane;
    int m0 = blockIdx.y*16 + wv*4;
    int type = c >> 9;
    const f4* x4 = (const f4*)x;
    const f4* h4 = (const f4*)h;
    float acc[4] = {0,0,0,0};
    float bias;
    if (type <= 1){
        const f4* wi = (const f4*)(Wih + (size_t)c*DD);
        const f4* wh = (const f4*)(Whh + (size_t)c*DD);
        for (int k = 0; k < 128; k++){
            f4 aa = wi[k], bb = wh[k];
#pragma unroll
            for (int mm = 0; mm < 4; mm++)
                acc[mm] += dot4f(aa, x4[(size_t)(m0+mm)*128+k]) + dot4f(bb, h4[(size_t)(m0+mm)*128+k]);
        }
        bias = bih[c] + bhh[c];
    } else if (type == 2){
        const f4* wi = (const f4*)(Wih + (size_t)c*DD);
        for (int k = 0; k < 128; k++){
            f4 aa = wi[k];
#pragma unroll
            for (int mm = 0; mm < 4; mm++)
                acc[mm] += dot4f(aa, x4[(size_t)(m0+mm)*128+k]);
        }
        bias = bih[c];
    } else {
        int cr = c - 512;
        const f4* wh = (const f4*)(Whh + (size_t)cr*DD);
        for (int k = 0; k < 128; k++){
            f4 aa = wh[k];
#pragma unroll
            for (int mm = 0; mm < 4; mm++)
                acc[mm] += dot4f(aa, h4[(size_t)(m0+mm)*128+k]);
        }
        bias = bhh[cr];
    }
#pragma unroll
    for (int mm = 0; mm < 4; mm++)
        gp[(size_t)(m0+mm)*2048 + c] = acc[mm] + bias;
}

// ---- GRU elementwise + LN(gff,bff) fused ----
__global__ __launch_bounds__(256) void k_gru_ln(const float* __restrict__ gp,
        const float* __restrict__ h, const float* __restrict__ gff, const float* __restrict__ bff,
        float* __restrict__ slots2, float* __restrict__ sbuf){
    __shared__ float sm[8];
    int m = blockIdx.x, t = threadIdx.x, lane = t & 63, wv = t >> 6;
    const float* g = gp + (size_t)m*2048;
    float2 rp = *(const float2*)(g + 2*t);
    float2 zp = *(const float2*)(g + 512 + 2*t);
    float2 nx = *(const float2*)(g + 1024 + 2*t);
    float2 nh = *(const float2*)(g + 1536 + 2*t);
    float2 hh = *(const float2*)(h + (size_t)m*DD + 2*t);
    float2 s2;
    {
        float r = 1.f/(1.f + __expf(-rp.x));
        float z = 1.f/(1.f + __expf(-zp.x));
        float n = tanhf(nx.x + r*nh.x);
        s2.x = (1.f - z)*n + z*hh.x;
        r = 1.f/(1.f + __expf(-rp.y));
        z = 1.f/(1.f + __expf(-zp.y));
        n = tanhf(nx.y + r*nh.y);
        s2.y = (1.f - z)*n + z*hh.y;
    }
    *(float2*)(slots2 + (size_t)m*DD + 2*t) = s2;
    float s = s2.x + s2.y;
    float ss = s2.x*s2.x + s2.y*s2.y;
    for (int o = 32; o; o >>= 1){ s += __shfl_down(s,o); ss += __shfl_down(ss,o); }
    if (lane == 0){ sm[wv] = s; sm[4+wv] = ss; }
    __syncthreads();
    float S = sm[0]+sm[1]+sm[2]+sm[3];
    float SS = sm[4]+sm[5]+sm[6]+sm[7];
    float mu = S*(1.f/DD);
    float rstd = rsqrtf(SS*(1.f/DD) - mu*mu + LN_EPS_F);
    float2 gg = *(const float2*)(gff + 2*t);
    float2 bb = *(const float2*)(bff + 2*t);
    float2 o2;
    o2.x = (s2.x-mu)*rstd*gg.x + bb.x;
    o2.y = (s2.y-mu)*rstd*gg.y + bb.y;
    *(float2*)(sbuf + (size_t)m*DD + 2*t) = o2;
}

// ---- FFN1 ----
__global__ __launch_bounds__(256) void k_ffn1(const float* __restrict__ a, const float* __restrict__ W1,
                                              const float* __restrict__ b1, float* __restrict__ hid){
    int lane = threadIdx.x & 63, wv = threadIdx.x >> 6;
    int c = blockIdx.x*64 + lane;
    int m0 = blockIdx.y*16 + wv*4;
    const f4* w4 = (const f4*)(W1 + (size_t)c*DD);
    const f4* a4 = (const f4*)a;
    float acc[4] = {0,0,0,0};
    for (int k = 0; k < 128; k++){
        f4 w = w4[k];
#pragma unroll
        for (int mm = 0; mm < 4; mm++)
            acc[mm] += dot4f(w, a4[(size_t)(m0+mm)*128+k]);
    }
    float bc = b1[c];
#pragma unroll
    for (int mm = 0; mm < 4; mm++)
        hid[(size_t)(m0+mm)*DD + c] = fmaxf(acc[mm] + bc, 0.f);
}

// ---- FFN2 ----
__global__ __launch_bounds__(256) void k_ffn2(const float* __restrict__ hid, const float* __restrict__ W2,
                                              const float* __restrict__ b2, const float* __restrict__ slots2,
                                              float* __restrict__ slots, float* __restrict__ out_slots, int last){
    int lane = threadIdx.x & 63, wv = threadIdx.x >> 6;
    int d = blockIdx.x*64 + lane;
    int m0 = blockIdx.y*16 + wv*4;
    const f4* w4 = (const f4*)(W2 + (size_t)d*DD);
    const f4* h4 = (const f4*)hid;
    float acc[4] = {0,0,0,0};
    for (int k = 0; k < 128; k++){
        f4 w = w4[k];
#pragma unroll
        for (int mm = 0; mm < 4; mm++)
            acc[mm] += dot4f(w, h4[(size_t)(m0+mm)*128+k]);
    }
    float bc = b2[d];
#pragma unroll
    for (int mm = 0; mm < 4; mm++){
        float v0 = slots2[(size_t)(m0+mm)*DD + d] + acc[mm] + bc;
        slots[(size_t)(m0+mm)*DD + d] = v0;
        if (last) out_slots[(size_t)(m0+mm)*DD + d] = v0;
    }
}

// ---- features ----
__global__ __launch_bounds__(256) void k_features(const float* __restrict__ prompts, const float* __restrict__ slots,
        const float* __restrict__ attn, float* __restrict__ pf, float* __restrict__ sf, float* __restrict__ sf2){
    int b = blockIdx.y;
    int pbase = blockIdx.x*32;
    int t = threadIdx.x;
    __shared__ float al[NSL][33];
    for (int idx = t; idx < NSL*32; idx += 256){
        int i = idx >> 5, pp = idx & 31;
        al[i][pp] = attn[((size_t)b*NSL + i)*NN + pbase + pp];
    }
    float2 pr[NSL], sl[NSL];
    const float2* p2 = (const float2*)prompts;
    const float2* s2 = (const float2*)(slots + (size_t)b*NSL*DD);
#pragma unroll
    for (int i = 0; i < NSL; i++){ pr[i] = p2[i*256+t]; sl[i] = s2[i*256+t]; }
    __syncthreads();
    for (int pp = 0; pp < 32; pp++){
        float a0=0.f, a1=0.f, c0=0.f, c1=0.f;
#pragma unroll
        for (int i = 0; i < NSL; i++){
            float a = al[i][pp];
            a0 += a*pr[i].x; a1 += a*pr[i].y;
            c0 += a*sl[i].x; c1 += a*sl[i].y;
        }
        size_t o = ((size_t)b*NN + pbase + pp)*DD + 2*t;
        float2 pv; pv.x=a0; pv.y=a1;
        float2 sv; sv.x=c0; sv.y=c1;
        *(float2*)(pf + o)  = pv;
        *(float2*)(sf + o)  = sv;
        *(float2*)(sf2 + o) = sv;
    }
}

extern "C" void kernel_launch(void* const* d_in, const int* in_sizes, int n_in,
                              void* d_out, int out_size, void* d_ws, size_t ws_size,
                              hipStream_t stream) {
    const float* k_inp   = (const float*)d_in[2];
    const float* v_inp   = (const float*)d_in[3];
    const float* slots_mu= (const float*)d_in[4];
    const float* prompts = (const float*)d_in[5];
    const float* Wq      = (const float*)d_in[6];
    const float* bq      = (const float*)d_in[7];
    const float* W_ih    = (const float*)d_in[8];
    const float* b_ih    = (const float*)d_in[9];
    const float* W_hh    = (const float*)d_in[10];
    const float* b_hh    = (const float*)d_in[11];
    const float* W1      = (const float*)d_in[12];
    const float* b1      = (const float*)d_in[13];
    const float* W2      = (const float*)d_in[14];
    const float* b2      = (const float*)d_in[15];
    const float* gk      = (const float*)d_in[16];
    const float* bk      = (const float*)d_in[17];
    const float* gv      = (const float*)d_in[18];
    const float* bv      = (const float*)d_in[19];
    const float* gs      = (const float*)d_in[20];
    const float* bs      = (const float*)d_in[21];
    const float* gff     = (const float*)d_in[22];
    const float* bff     = (const float*)d_in[23];

    float* ws = (float*)d_ws;
    float* slots   = ws + 0;
    float* slots2  = ws + 131072;
    float* sbuf    = ws + 262144;
    float* qg      = ws + 393216;
    float* upd     = ws + 524288;
    float* hid     = ws + 655360;
    float* gp      = ws + 786432;     // 524288 -> ends 1310720
    float* C1p     = ws + 1310720;    // 2048
    float* C2p     = ws + 1312768;    // 2048
    float* kmu     = ws + 1314816;    // 65536
    float* krstd   = ws + 1380352;    // 65536
    float* vmu     = ws + 1445888;    // 65536
    float* vrstd   = ws + 1511424;    // 65536
    float* Sp      = ws + 1576960;    // 4096
    float* Mp      = ws + 1581056;    // 4096 -> ends 1585152 (6.3 MB)

    float* out      = (float*)d_out;
    float* attn_out = out + 131072;
    float* pf       = out + 1179648;
    float* sf       = pf + 33554432;
    float* sf2      = sf + 33554432;
    float* Uwp      = pf;             // 2.1M floats scratch; overwritten by k_features

    k_pre<<<512, 256, 0, stream>>>(slots_mu, k_inp, v_inp, slots, kmu, krstd, vmu, vrstd);

    for (int it = 0; it < 3; it++){
        int last = (it == 2);
        k_ln_q<<<dim3(8,64), 256, 0, stream>>>(slots, gs, bs, Wq, bq, gk, bk, qg, C1p, C2p);
        k_attn_av<<<dim3(16,16), 256, 0, stream>>>(k_inp, v_inp, qg, C1p, C2p,
                                                   kmu, krstd, vmu, vrstd,
                                                   Sp, Mp, Uwp, attn_out, last);
        k_upd<<<256, 256, 0, stream>>>(Uwp, Sp, Mp, gv, bv, upd);
        k_gru_mm<<<dim3(32,16), 256, 0, stream>>>(upd, slots, W_ih, b_ih, W_hh, b_hh, gp);
        k_gru_ln<<<256, 256, 0, stream>>>(gp, slots, gff, bff, slots2, sbuf);
        k_ffn1<<<dim3(8,16), 256, 0, stream>>>(sbuf, W1, b1, hid);
        k_ffn2<<<dim3(8,16), 256, 0, stream>>>(hid, W2, b2, slots2, slots, out, last);
    }

    k_features<<<dim3(128,16), 256, 0, stream>>>(prompts, slots, attn_out, pf, sf, sf2);
}

// Round 8
// 1179.771 us; speedup vs baseline: 2.6633x; 1.0234x over previous
//
#include <hip/hip_runtime.h>
#include <math.h>

#define NN 4096
#define DD 512
#define NSL 16
#define SCALE_F 0.044194173824159216f
#define LN_EPS_F 1e-5f
#define ATTN_EPS_F 1e-8f

typedef float4 f4;
typedef __fp16 h2 __attribute__((ext_vector_type(2)));      // cvt_pkrtz return type
typedef _Float16 h2f __attribute__((ext_vector_type(2)));   // fdot2 operand type

#if defined(__has_builtin)
#if __has_builtin(__builtin_amdgcn_fdot2) && __has_builtin(__builtin_amdgcn_cvt_pkrtz)
#define USE_FDOT2 1
#endif
#endif

__device__ __forceinline__ float dot4f(f4 a, f4 b){
    return a.x*b.x + a.y*b.y + a.z*b.z + a.w*b.w;
}

#ifdef USE_FDOT2
__device__ __forceinline__ float fdot2f(h2 a, h2 b, float c){
    return __builtin_amdgcn_fdot2(__builtin_bit_cast(h2f, a),
                                  __builtin_bit_cast(h2f, b), c, false);
}
__device__ __forceinline__ unsigned pk(float x, float y){
    return __builtin_bit_cast(unsigned, __builtin_amdgcn_cvt_pkrtz(x, y));
}
#endif

// ---- pre: slots bcast + per-row stats of v and k, coalesced 16-lanes/row ----
// grid 1024 x 256: 4 blocks/CU, 16 waves/CU.
__global__ __launch_bounds__(256) void k_pre(const float* __restrict__ mu,
        const float* __restrict__ kin, const float* __restrict__ vin,
        float* __restrict__ slots, float* __restrict__ kmu, float* __restrict__ krstd,
        float* __restrict__ vmu, float* __restrict__ vrstd){
    int bx = blockIdx.x, t = threadIdx.x;
    if (bx < 128){
        int idx = bx*256 + t;                      // 32768 f4
        ((f4*)slots)[idx] = ((const f4*)mu)[idx & 2047];
    }
    int sub = t & 15;            // lane within row
    int rl  = t >> 4;            // 16 rows per pass
#pragma unroll
    for (int pass = 0; pass < 8; pass++){
        int task = bx*128 + pass*16 + rl;          // 0..131071
        int half = task >> 16;                     // 0: v, 1: k
        int row  = task & 65535;
        const float* src = half ? kin : vin;
        const f4* r4 = (const f4*)(src + (size_t)row*DD);
        float s = 0.f, ss = 0.f;
#pragma unroll
        for (int k2 = 0; k2 < 8; k2++){
            f4 x = r4[sub + k2*16];
            s  += x.x+x.y+x.z+x.w;
            ss += x.x*x.x+x.y*x.y+x.z*x.z+x.w*x.w;
        }
        for (int o = 1; o < 16; o <<= 1){
            s += __shfl_xor(s, o); ss += __shfl_xor(ss, o);
        }
        if (sub == 0){
            float m = s*(1.f/DD);
            float rs = rsqrtf(ss*(1.f/DD) - m*m + LN_EPS_F);
            if (half){ kmu[row] = m; krstd[row] = rs; }
            else     { vmu[row] = m; vrstd[row] = rs; }
        }
    }
}

// ---- fused LN(slots) + q-projection ----
__global__ __launch_bounds__(256) void k_ln_q(const float* __restrict__ slots,
        const float* __restrict__ gs, const float* __restrict__ bs,
        const float* __restrict__ Wq, const float* __restrict__ bq,
        const float* __restrict__ gk, const float* __restrict__ bk,
        float* __restrict__ qg, float* __restrict__ C1p, float* __restrict__ C2p){
    __shared__ __align__(16) float rowL[4*DD];
    int lane = threadIdx.x & 63, wv = threadIdx.x >> 6;
    int m = blockIdx.y*4 + wv;
    int c = blockIdx.x*64 + lane;
    const f4* r4 = (const f4*)(slots + (size_t)m*DD);
    f4 v0 = r4[lane*2], v1 = r4[lane*2+1];
    float s  = v0.x+v0.y+v0.z+v0.w + v1.x+v1.y+v1.z+v1.w;
    float ss = v0.x*v0.x+v0.y*v0.y+v0.z*v0.z+v0.w*v0.w
             + v1.x*v1.x+v1.y*v1.y+v1.z*v1.z+v1.w*v1.w;
    for (int o = 32; o; o >>= 1){ s += __shfl_down(s,o); ss += __shfl_down(ss,o); }
    s = __shfl(s,0); ss = __shfl(ss,0);
    float mu = s*(1.f/DD);
    float rstd = rsqrtf(ss*(1.f/DD) - mu*mu + LN_EPS_F);
    const f4* g4 = (const f4*)gs; const f4* b4 = (const f4*)bs;
    f4 g0 = g4[lane*2], g1 = g4[lane*2+1], c0 = b4[lane*2], c1 = b4[lane*2+1];
    f4 o0, o1;
    o0.x=(v0.x-mu)*rstd*g0.x+c0.x; o0.y=(v0.y-mu)*rstd*g0.y+c0.y;
    o0.z=(v0.z-mu)*rstd*g0.z+c0.z; o0.w=(v0.w-mu)*rstd*g0.w+c0.w;
    o1.x=(v1.x-mu)*rstd*g1.x+c1.x; o1.y=(v1.y-mu)*rstd*g1.y+c1.y;
    o1.z=(v1.z-mu)*rstd*g1.z+c1.z; o1.w=(v1.w-mu)*rstd*g1.w+c1.w;
    f4* rw = (f4*)(rowL + wv*DD);
    rw[lane*2] = o0; rw[lane*2+1] = o1;
    __syncthreads();
    const f4* w4 = (const f4*)(Wq + (size_t)c*DD);
    float acc = 0.f;
    for (int k = 0; k < 128; k++) acc += dot4f(rw[k], w4[k]);
    float q0 = acc + bq[c];
    float qg0 = q0 * gk[c];
    qg[(size_t)m*DD + c] = qg0;
    float r1 = qg0, r2 = q0 * bk[c];
    for (int o = 32; o; o >>= 1){ r1 += __shfl_down(r1,o); r2 += __shfl_down(r2,o); }
    if (lane == 0){
        C1p[blockIdx.x*256 + m] = r1;
        C2p[blockIdx.x*256 + m] = r2;
    }
}

// ---- fused QK^T + inverted softmax + AV partial ----
// grid (64 chunks of 64 j, 16 b) = 1024 blocks, 4/CU, 16 waves/CU.
// QK: lane = (quarter q, row r): row j = chunk*64 + wv*16 + r, D-quarter q.
__global__ __launch_bounds__(256, 4) void k_attn_av(const float* __restrict__ kin,
        const float* __restrict__ vin, const float* __restrict__ qg,
        const float* __restrict__ C1p, const float* __restrict__ C2p,
        const float* __restrict__ kmu, const float* __restrict__ krstd,
        const float* __restrict__ vmu, const float* __restrict__ vrstd,
        float* __restrict__ Sp, float* __restrict__ Mp, float* __restrict__ Uwp,
        float* __restrict__ attn_out, int last){
#ifdef USE_FDOT2
    __shared__ __align__(16) uint4 qhL[1024];      // 16 KB packed f16
#else
    __shared__ __align__(16) f4 qgL[2048];         // 32 KB fp32
#endif
    __shared__ __align__(16) float wL[64*20];      // 5 KB
    __shared__ float c1s[NSL], c2s[NSL];
    __shared__ float spL[4][NSL], mpL[4][NSL];
    int chunk = blockIdx.x, b = blockIdx.y;
    int t = threadIdx.x, lane = t & 63, wv = t >> 6;
    int r = lane & 15, qq = lane >> 4;

    const f4* qgg = (const f4*)(qg + (size_t)b*NSL*DD);
#ifdef USE_FDOT2
    for (int e = t; e < 1024; e += 256){
        int dd = e >> 3, p = e & 7;
        f4 qa = qgg[(size_t)(2*p)*128 + dd];
        f4 qb = qgg[(size_t)(2*p+1)*128 + dd];
        uint4 u;
        u.x = pk(qa.x, qa.y);
        u.y = pk(qb.x, qb.y);
        u.z = pk(qa.z, qa.w);
        u.w = pk(qb.z, qb.w);
        qhL[e] = u;
    }
#else
    for (int e = t; e < 2048; e += 256) qgL[e] = qgg[e];
#endif
    if (t < NSL){
        float c1 = 0.f, c2 = 0.f;
#pragma unroll
        for (int k = 0; k < 8; k++){
            c1 += C1p[k*256 + b*NSL + t];
            c2 += C2p[k*256 + b*NSL + t];
        }
        c1s[t] = c1; c2s[t] = c2;
    }
    __syncthreads();

    // ---- QK: thread owns quarter qq of row j ----
    int j = chunk*64 + wv*16 + r;
    const f4* kr = (const f4*)(kin + ((size_t)b*NN + j)*DD) + qq*32;
    float a[NSL];
#pragma unroll
    for (int i = 0; i < NSL; i++) a[i] = 0.f;
    f4 kv = kr[0];
    for (int dd2 = 0; dd2 < 32; dd2++){
        f4 nk;
        if (dd2 < 31) nk = kr[dd2+1];
        int dd = qq*32 + dd2;
#ifdef USE_FDOT2
        h2 k01 = __builtin_amdgcn_cvt_pkrtz(kv.x, kv.y);
        h2 k23 = __builtin_amdgcn_cvt_pkrtz(kv.z, kv.w);
#pragma unroll
        for (int p = 0; p < 8; p++){
            uint4 u = qhL[dd*8 + p];
            h2 q0a = __builtin_bit_cast(h2, u.x);
            h2 q1a = __builtin_bit_cast(h2, u.y);
            h2 q0b = __builtin_bit_cast(h2, u.z);
            h2 q1b = __builtin_bit_cast(h2, u.w);
            a[2*p]   = fdot2f(k01, q0a, a[2*p]);
            a[2*p]   = fdot2f(k23, q0b, a[2*p]);
            a[2*p+1] = fdot2f(k01, q1a, a[2*p+1]);
            a[2*p+1] = fdot2f(k23, q1b, a[2*p+1]);
        }
#else
#pragma unroll
        for (int i = 0; i < NSL; i++) a[i] += dot4f(qgL[i*128+dd], kv);
#endif
        kv = nk;
    }
    // combine the 4 quarters (lanes differing in bits 4,5)
#pragma unroll
    for (int i = 0; i < NSL; i++){
        a[i] += __shfl_xor(a[i], 16);
        a[i] += __shfl_xor(a[i], 32);
    }
    float mu = kmu[(size_t)b*NN + j];
    float rstd = krstd[(size_t)b*NN + j];
    float mx = -1e30f;
#pragma unroll
    for (int i = 0; i < NSL; i++){
        a[i] = SCALE_F*(rstd*(a[i] - mu*c1s[i]) + c2s[i]);
        mx = fmaxf(mx, a[i]);
    }
    float se = 0.f;
#pragma unroll
    for (int i = 0; i < NSL; i++){ a[i] = __expf(a[i]-mx); se += a[i]; }
    float inv = 1.f/se;
    float rv = vrstd[(size_t)b*NN + j];
    float vm = vmu[(size_t)b*NN + j];
#pragma unroll
    for (int i = 0; i < NSL; i++) a[i] = a[i]*inv + ATTN_EPS_F;
    // per-wave partials over the 16 rows (values quarter-replicated; xor 1..8
    // stays within each 16-lane group, so no overcount)
#pragma unroll
    for (int i = 0; i < NSL; i++){
        float r1 = a[i], r2 = a[i]*rv*vm;
        for (int o = 1; o < 16; o <<= 1){ r1 += __shfl_xor(r1,o); r2 += __shfl_xor(r2,o); }
        if (lane == 0){ spL[wv][i] = r1; mpL[wv][i] = r2; }
    }
    if (qq == 0){
        int jl = wv*16 + r;
#pragma unroll
        for (int i = 0; i < NSL; i++) wL[jl*20 + i] = a[i]*rv;
        if (last){
#pragma unroll
            for (int i = 0; i < NSL; i++)
                attn_out[((size_t)b*NSL + i)*NN + j] = a[i];
        }
    }
    __syncthreads();

    if (t < NSL)
        Sp[((size_t)b*NSL + t)*64 + chunk] = spL[0][t]+spL[1][t]+spL[2][t]+spL[3][t];
    else if (t < 2*NSL){
        int i = t - NSL;
        Mp[((size_t)b*NSL + i)*64 + chunk] = mpL[0][i]+mpL[1][i]+mpL[2][i]+mpL[3][i];
    }

    // ---- AV partial over this chunk's 64 j ----
    f4 ax[4], ay[4];
#pragma unroll
    for (int g2 = 0; g2 < 4; g2++){ ax[g2] = f4{0,0,0,0}; ay[g2] = f4{0,0,0,0}; }
    const float2* v2 = (const float2*)(vin + ((size_t)b*NN + (size_t)chunk*64)*DD);
#pragma unroll 2
    for (int jj = 0; jj < 64; jj++){
        float2 vv = v2[(size_t)jj*256 + t];
        const f4* wl4 = (const f4*)(wL + jj*20);
#pragma unroll
        for (int g2 = 0; g2 < 4; g2++){
            f4 wq = wl4[g2];
            ax[g2].x += wq.x*vv.x; ax[g2].y += wq.y*vv.x; ax[g2].z += wq.z*vv.x; ax[g2].w += wq.w*vv.x;
            ay[g2].x += wq.x*vv.y; ay[g2].y += wq.y*vv.y; ay[g2].z += wq.z*vv.y; ay[g2].w += wq.w*vv.y;
        }
    }
#pragma unroll
    for (int g2 = 0; g2 < 4; g2++){
        const float* px = (const float*)&ax[g2];
        const float* py = (const float*)&ay[g2];
#pragma unroll
        for (int c4 = 0; c4 < 4; c4++){
            int i = g2*4 + c4;
            float2 o2; o2.x = px[c4]; o2.y = py[c4];
            *(float2*)(Uwp + (((size_t)(b*NSL + i))*64 + chunk)*DD + 2*t) = o2;
        }
    }
}

// ---- updates = gv*(sum Uwp - M)/S + bv  (block = row m) ----
__global__ __launch_bounds__(256) void k_upd(const float* __restrict__ Uwp,
        const float* __restrict__ Sp, const float* __restrict__ Mp,
        const float* __restrict__ gv, const float* __restrict__ bv,
        float* __restrict__ upd){
    __shared__ float sm[2];
    int m = blockIdx.x, t = threadIdx.x;
    if (t < 128){
        float val = (t < 64) ? Sp[(size_t)m*64 + (t&63)] : Mp[(size_t)m*64 + (t&63)];
        for (int o = 1; o < 64; o <<= 1) val += __shfl_xor(val, o);
        if (t == 0)  sm[0] = val;
        if (t == 64) sm[1] = val;
    }
    __syncthreads();
    float Sv = sm[0], Mv = sm[1];
    float rS = 1.f/Sv;
    float2 acc; acc.x = 0.f; acc.y = 0.f;
    const float* base = Uwp + (size_t)m*64*DD + 2*t;
#pragma unroll 8
    for (int ch = 0; ch < 64; ch++){
        float2 u = *(const float2*)(base + (size_t)ch*DD);
        acc.x += u.x; acc.y += u.y;
    }
    float2 gvv = ((const float2*)gv)[t];
    float2 bvv = ((const float2*)bv)[t];
    float2 o2;
    o2.x = gvv.x*(acc.x - Mv)*rS + bvv.x;
    o2.y = gvv.y*(acc.y - Mv)*rS + bvv.y;
    *(float2*)(upd + (size_t)m*DD + 2*t) = o2;
}

// ---- GRU gate matmuls ----
__global__ __launch_bounds__(256) void k_gru_mm(const float* __restrict__ x, const float* __restrict__ h,
        const float* __restrict__ Wih, const float* __restrict__ bih,
        const float* __restrict__ Whh, const float* __restrict__ bhh,
        float* __restrict__ gp){
    int lane = threadIdx.x & 63, wv = threadIdx.x >> 6;
    int c = blockIdx.x*64 + lane;
    int m0 = blockIdx.y*16 + wv*4;
    int type = c >> 9;
    const f4* x4 = (const f4*)x;
    const f4* h4 = (const f4*)h;
    float acc[4] = {0,0,0,0};
    float bias;
    if (type <= 1){
        const f4* wi = (const f4*)(Wih + (size_t)c*DD);
        const f4* wh = (const f4*)(Whh + (size_t)c*DD);
        for (int k = 0; k < 128; k++){
            f4 aa = wi[k], bb = wh[k];
#pragma unroll
            for (int mm = 0; mm < 4; mm++)
                acc[mm] += dot4f(aa, x4[(size_t)(m0+mm)*128+k]) + dot4f(bb, h4[(size_t)(m0+mm)*128+k]);
        }
        bias = bih[c] + bhh[c];
    } else if (type == 2){
        const f4* wi = (const f4*)(Wih + (size_t)c*DD);
        for (int k = 0; k < 128; k++){
            f4 aa = wi[k];
#pragma unroll
            for (int mm = 0; mm < 4; mm++)
                acc[mm] += dot4f(aa, x4[(size_t)(m0+mm)*128+k]);
        }
        bias = bih[c];
    } else {
        int cr = c - 512;
        const f4* wh = (const f4*)(Whh + (size_t)cr*DD);
        for (int k = 0; k < 128; k++){
            f4 aa = wh[k];
#pragma unroll
            for (int mm = 0; mm < 4; mm++)
                acc[mm] += dot4f(aa, h4[(size_t)(m0+mm)*128+k]);
        }
        bias = bhh[cr];
    }
#pragma unroll
    for (int mm = 0; mm < 4; mm++)
        gp[(size_t)(m0+mm)*2048 + c] = acc[mm] + bias;
}

// ---- GRU elementwise + LN(gff,bff) fused ----
__global__ __launch_bounds__(256) void k_gru_ln(const float* __restrict__ gp,
        const float* __restrict__ h, const float* __restrict__ gff, const float* __restrict__ bff,
        float* __restrict__ slots2, float* __restrict__ sbuf){
    __shared__ float sm[8];
    int m = blockIdx.x, t = threadIdx.x, lane = t & 63, wv = t >> 6;
    const float* g = gp + (size_t)m*2048;
    float2 rp = *(const float2*)(g + 2*t);
    float2 zp = *(const float2*)(g + 512 + 2*t);
    float2 nx = *(const float2*)(g + 1024 + 2*t);
    float2 nh = *(const float2*)(g + 1536 + 2*t);
    float2 hh = *(const float2*)(h + (size_t)m*DD + 2*t);
    float2 s2;
    {
        float r = 1.f/(1.f + __expf(-rp.x));
        float z = 1.f/(1.f + __expf(-zp.x));
        float n = tanhf(nx.x + r*nh.x);
        s2.x = (1.f - z)*n + z*hh.x;
        r = 1.f/(1.f + __expf(-rp.y));
        z = 1.f/(1.f + __expf(-zp.y));
        n = tanhf(nx.y + r*nh.y);
        s2.y = (1.f - z)*n + z*hh.y;
    }
    *(float2*)(slots2 + (size_t)m*DD + 2*t) = s2;
    float s = s2.x + s2.y;
    float ss = s2.x*s2.x + s2.y*s2.y;
    for (int o = 32; o; o >>= 1){ s += __shfl_down(s,o); ss += __shfl_down(ss,o); }
    if (lane == 0){ sm[wv] = s; sm[4+wv] = ss; }
    __syncthreads();
    float S = sm[0]+sm[1]+sm[2]+sm[3];
    float SS = sm[4]+sm[5]+sm[6]+sm[7];
    float mu = S*(1.f/DD);
    float rstd = rsqrtf(SS*(1.f/DD) - mu*mu + LN_EPS_F);
    float2 gg = *(const float2*)(gff + 2*t);
    float2 bb = *(const float2*)(bff + 2*t);
    float2 o2;
    o2.x = (s2.x-mu)*rstd*gg.x + bb.x;
    o2.y = (s2.y-mu)*rstd*gg.y + bb.y;
    *(float2*)(sbuf + (size_t)m*DD + 2*t) = o2;
}

// ---- FFN1 ----
__global__ __launch_bounds__(256) void k_ffn1(const float* __restrict__ a, const float* __restrict__ W1,
                                              const float* __restrict__ b1, float* __restrict__ hid){
    int lane = threadIdx.x & 63, wv = threadIdx.x >> 6;
    int c = blockIdx.x*64 + lane;
    int m0 = blockIdx.y*16 + wv*4;
    const f4* w4 = (const f4*)(W1 + (size_t)c*DD);
    const f4* a4 = (const f4*)a;
    float acc[4] = {0,0,0,0};
    for (int k = 0; k < 128; k++){
        f4 w = w4[k];
#pragma unroll
        for (int mm = 0; mm < 4; mm++)
            acc[mm] += dot4f(w, a4[(size_t)(m0+mm)*128+k]);
    }
    float bc = b1[c];
#pragma unroll
    for (int mm = 0; mm < 4; mm++)
        hid[(size_t)(m0+mm)*DD + c] = fmaxf(acc[mm] + bc, 0.f);
}

// ---- FFN2 ----
__global__ __launch_bounds__(256) void k_ffn2(const float* __restrict__ hid, const float* __restrict__ W2,
                                              const float* __restrict__ b2, const float* __restrict__ slots2,
                                              float* __restrict__ slots, float* __restrict__ out_slots, int last){
    int lane = threadIdx.x & 63, wv = threadIdx.x >> 6;
    int d = blockIdx.x*64 + lane;
    int m0 = blockIdx.y*16 + wv*4;
    const f4* w4 = (const f4*)(W2 + (size_t)d*DD);
    const f4* h4 = (const f4*)hid;
    float acc[4] = {0,0,0,0};
    for (int k = 0; k < 128; k++){
        f4 w = w4[k];
#pragma unroll
        for (int mm = 0; mm < 4; mm++)
            acc[mm] += dot4f(w, h4[(size_t)(m0+mm)*128+k]);
    }
    float bc = b2[d];
#pragma unroll
    for (int mm = 0; mm < 4; mm++){
        float v0 = slots2[(size_t)(m0+mm)*DD + d] + acc[mm] + bc;
        slots[(size_t)(m0+mm)*DD + d] = v0;
        if (last) out_slots[(size_t)(m0+mm)*DD + d] = v0;
    }
}

// ---- features ----
__global__ __launch_bounds__(256) void k_features(const float* __restrict__ prompts, const float* __restrict__ slots,
        const float* __restrict__ attn, float* __restrict__ pf, float* __restrict__ sf, float* __restrict__ sf2){
    int b = blockIdx.y;
    int pbase = blockIdx.x*32;
    int t = threadIdx.x;
    __shared__ float al[NSL][33];
    for (int idx = t; idx < NSL*32; idx += 256){
        int i = idx >> 5, pp = idx & 31;
        al[i][pp] = attn[((size_t)b*NSL + i)*NN + pbase + pp];
    }
    float2 pr[NSL], sl[NSL];
    const float2* p2 = (const float2*)prompts;
    const float2* s2 = (const float2*)(slots + (size_t)b*NSL*DD);
#pragma unroll
    for (int i = 0; i < NSL; i++){ pr[i] = p2[i*256+t]; sl[i] = s2[i*256+t]; }
    __syncthreads();
    for (int pp = 0; pp < 32; pp++){
        float a0=0.f, a1=0.f, c0=0.f, c1=0.f;
#pragma unroll
        for (int i = 0; i < NSL; i++){
            float a = al[i][pp];
            a0 += a*pr[i].x; a1 += a*pr[i].y;
            c0 += a*sl[i].x; c1 += a*sl[i].y;
        }
        size_t o = ((size_t)b*NN + pbase + pp)*DD + 2*t;
        float2 pv; pv.x=a0; pv.y=a1;
        float2 sv; sv.x=c0; sv.y=c1;
        *(float2*)(pf + o)  = pv;
        *(float2*)(sf + o)  = sv;
        *(float2*)(sf2 + o) = sv;
    }
}

extern "C" void kernel_launch(void* const* d_in, const int* in_sizes, int n_in,
                              void* d_out, int out_size, void* d_ws, size_t ws_size,
                              hipStream_t stream) {
    const float* k_inp   = (const float*)d_in[2];
    const float* v_inp   = (const float*)d_in[3];
    const float* slots_mu= (const float*)d_in[4];
    const float* prompts = (const float*)d_in[5];
    const float* Wq      = (const float*)d_in[6];
    const float* bq      = (const float*)d_in[7];
    const float* W_ih    = (const float*)d_in[8];
    const float* b_ih    = (const float*)d_in[9];
    const float* W_hh    = (const float*)d_in[10];
    const float* b_hh    = (const float*)d_in[11];
    const float* W1      = (const float*)d_in[12];
    const float* b1      = (const float*)d_in[13];
    const float* W2      = (const float*)d_in[14];
    const float* b2      = (const float*)d_in[15];
    const float* gk      = (const float*)d_in[16];
    const float* bk      = (const float*)d_in[17];
    const float* gv      = (const float*)d_in[18];
    const float* bv      = (const float*)d_in[19];
    const float* gs      = (const float*)d_in[20];
    const float* bs      = (const float*)d_in[21];
    const float* gff     = (const float*)d_in[22];
    const float* bff     = (const float*)d_in[23];

    float* ws = (float*)d_ws;
    float* slots   = ws + 0;
    float* slots2  = ws + 131072;
    float* sbuf    = ws + 262144;
    float* qg      = ws + 393216;
    float* upd     = ws + 524288;
    float* hid     = ws + 655360;
    float* gp      = ws + 786432;     // 524288 -> ends 1310720
    float* C1p     = ws + 1310720;    // 2048
    float* C2p     = ws + 1312768;    // 2048
    float* kmu     = ws + 1314816;    // 65536
    float* krstd   = ws + 1380352;    // 65536
    float* vmu     = ws + 1445888;    // 65536
    float* vrstd   = ws + 1511424;    // 65536
    float* Sp      = ws + 1576960;    // 16384
    float* Mp      = ws + 1593344;    // 16384 -> ends 1609728 (6.4 MB)

    float* out      = (float*)d_out;
    float* attn_out = out + 131072;
    float* pf       = out + 1179648;
    float* sf       = pf + 33554432;
    float* sf2      = sf + 33554432;
    float* Uwp      = pf;             // 8.4M floats scratch; overwritten by k_features

    k_pre<<<1024, 256, 0, stream>>>(slots_mu, k_inp, v_inp, slots, kmu, krstd, vmu, vrstd);

    for (int it = 0; it < 3; it++){
        int last = (it == 2);
        k_ln_q<<<dim3(8,64), 256, 0, stream>>>(slots, gs, bs, Wq, bq, gk, bk, qg, C1p, C2p);
        k_attn_av<<<dim3(64,16), 256, 0, stream>>>(k_inp, v_inp, qg, C1p, C2p,
                                                   kmu, krstd, vmu, vrstd,
                                                   Sp, Mp, Uwp, attn_out, last);
        k_upd<<<256, 256, 0, stream>>>(Uwp, Sp, Mp, gv, bv, upd);
        k_gru_mm<<<dim3(32,16), 256, 0, stream>>>(upd, slots, W_ih, b_ih, W_hh, b_hh, gp);
        k_gru_ln<<<256, 256, 0, stream>>>(gp, slots, gff, bff, slots2, sbuf);
        k_ffn1<<<dim3(8,16), 256, 0, stream>>>(sbuf, W1, b1, hid);
        k_ffn2<<<dim3(8,16), 256, 0, stream>>>(hid, W2, b2, slots2, slots, out, last);
    }

    k_features<<<dim3(128,16), 256, 0, stream>>>(prompts, slots, attn_out, pf, sf, sf2);
}